// Round 1
// baseline (329.930 us; speedup 1.0000x reference)
//
#include <hip/hip_runtime.h>
#include <hip/hip_bf16.h>

static constexpr int H = 512;
static constexpr int W = 512;
static constexpr int NIMG = 8;
static constexpr float BIGF = 1.0e6f;

// ws layout (floats):
//   F[16][H][W]  : 16 * 262144 floats = 16 MiB   (t<8: EDT^2 of a_t, t>=8: EDT^2 of b_{t-8})
//   maxsq[16]    : task = dir*8+img ; dir0 = max_{a} D_b, dir1 = max_{b} D_a
//   anyflag[16]  : t<8: any(a_t), t>=8: any(b_{t-8})

__global__ void k_init(float* __restrict__ maxsq, int* __restrict__ anyflag) {
    int t = threadIdx.x;
    if (t < 16) { maxsq[t] = 0.0f; anyflag[t] = 0; }
}

__global__ void k_col_edt(const float* __restrict__ A, const float* __restrict__ B,
                          float* __restrict__ F, int* __restrict__ anyflag) {
    int t   = blockIdx.x * blockDim.x + threadIdx.x;   // 0..8191
    int m16 = t >> 9;                                  // mask index 0..15 (block fully inside one mask)
    int col = t & (W - 1);
    const float* src = (m16 < NIMG) ? (A + (size_t)m16 * H * W)
                                    : (B + (size_t)(m16 - NIMG) * H * W);
    float* f = F + (size_t)m16 * H * W;

    // down pass: f[i] = d_down (distance to nearest True at index <= i, via float cummax like ref)
    float run = -BIGF;
    #pragma unroll 4
    for (int i = 0; i < H; ++i) {
        float px   = src[i * W + col];
        float cand = (px > 0.5f) ? (float)i : -BIGF;
        run = fmaxf(run, cand);
        f[i * W + col] = (float)i - run;
    }
    int colany = (run > -0.5f * BIGF) ? 1 : 0;
    if (__any(colany)) {
        if ((threadIdx.x & 63) == 0) atomicOr(&anyflag[m16], 1);
    }

    // up pass: fuse d_up, clamp, square
    float run2 = -BIGF;
    #pragma unroll 4
    for (int i = H - 1; i >= 0; --i) {
        float px   = src[i * W + col];
        float ridx = (float)(H - 1 - i);
        float cand = (px > 0.5f) ? ridx : -BIGF;
        run2 = fmaxf(run2, cand);
        float d_up   = ridx - run2;
        float d_down = f[i * W + col];
        float d1 = fminf(fminf(d_down, d_up), BIGF);
        f[i * W + col] = d1 * d1;
    }
}

__global__ void k_row_env(const float* __restrict__ A, const float* __restrict__ B,
                          const float* __restrict__ F, float* __restrict__ maxsq) {
    const int row  = blockIdx.x;      // 0..H-1
    const int task = blockIdx.y;      // 0..15
    const int img  = task & 7;
    const int dir  = task >> 3;       // 0: D_b at a-pixels ; 1: D_a at b-pixels
    const int fsel = (dir == 0) ? (NIMG + img) : img;
    const float* frow = F + (size_t)fsel * H * W + (size_t)row * W;
    const float* mrow = ((dir == 0) ? A : B) + (size_t)img * H * W + (size_t)row * W;

    __shared__ float sf[W];
    __shared__ float wmax[8];
    const int j = threadIdx.x;        // 0..W-1, block = 512
    sf[j] = frow[j];
    const bool mk = mrow[j] > 0.5f;
    __syncthreads();

    // exact lower envelope via expanding search with provable cutoff r^2 >= best
    float best = sf[j];
    for (int r = 1; r < W; ++r) {
        float rr = (float)(r * r);
        if (__all(rr >= best)) break;   // wave-uniform exact early exit
        int kl = j - r, kr = j + r;
        if (kl >= 0) best = fminf(best, rr + sf[kl]);
        if (kr < W)  best = fminf(best, rr + sf[kr]);
    }

    float v = mk ? best : 0.0f;
    #pragma unroll
    for (int off = 32; off > 0; off >>= 1)
        v = fmaxf(v, __shfl_down(v, off, 64));
    if ((j & 63) == 0) wmax[j >> 6] = v;
    __syncthreads();
    if (j == 0) {
        float m = wmax[0];
        #pragma unroll
        for (int w = 1; w < 8; ++w) m = fmaxf(m, wmax[w]);
        atomicMax((int*)&maxsq[task], __float_as_int(m));  // values >= 0: int order == float order
    }
}

__global__ void k_finalize(const float* __restrict__ maxsq, const int* __restrict__ anyflag,
                           float* __restrict__ out) {
    if (threadIdx.x == 0 && blockIdx.x == 0) {
        float s = 0.0f;
        for (int img = 0; img < NIMG; ++img) {
            bool empty = (anyflag[img] == 0) || (anyflag[NIMG + img] == 0);
            float loss;
            if (empty) {
                loss = 1.0f;
            } else {
                float hd = sqrtf(fmaxf(maxsq[img], maxsq[NIMG + img]));
                loss = 1.0f - 1.0f / (1.0f + hd);
            }
            s += loss;
        }
        out[0] = s * (1.0f / (float)NIMG);
    }
}

extern "C" void kernel_launch(void* const* d_in, const int* in_sizes, int n_in,
                              void* d_out, int out_size, void* d_ws, size_t ws_size,
                              hipStream_t stream) {
    const float* A = (const float*)d_in[0];
    const float* B = (const float*)d_in[1];
    float* F       = (float*)d_ws;
    float* maxsq   = F + (size_t)16 * H * W;
    int*   anyflag = (int*)(maxsq + 16);
    float* out     = (float*)d_out;

    hipLaunchKernelGGL(k_init, dim3(1), dim3(32), 0, stream, maxsq, anyflag);
    hipLaunchKernelGGL(k_col_edt, dim3((16 * W) / 128), dim3(128), 0, stream, A, B, F, anyflag);
    hipLaunchKernelGGL(k_row_env, dim3(H, 16), dim3(W), 0, stream, A, B, F, maxsq);
    hipLaunchKernelGGL(k_finalize, dim3(1), dim3(1), 0, stream, maxsq, anyflag, out);
}

// Round 2
// 136.524 us; speedup vs baseline: 2.4167x; 2.4167x over previous
//
#include <hip/hip_runtime.h>
#include <hip/hip_bf16.h>

static constexpr int H = 512;
static constexpr int W = 512;
static constexpr int NIMG = 8;
static constexpr float BIGF = 1.0e6f;

static constexpr int SEG  = 32;        // rows per segment (one bitmask word)
static constexpr int NSEG = H / SEG;   // 16 segments per column
static constexpr int CPB  = 32;        // columns per block

// ws layout (floats):
//   F[16][H][W]  : 16 MiB  (t<8: EDT^2 of a_t, t>=8: EDT^2 of b_{t-8})
//   maxsq[16]    : task = dir*8+img
//   anyflag[16]

__global__ void k_init(float* __restrict__ maxsq, int* __restrict__ anyflag) {
    int t = threadIdx.x;
    if (t < 16) { maxsq[t] = 0.0f; anyflag[t] = 0; }
}

__global__ __launch_bounds__(CPB * NSEG)
void k_col_edt(const float* __restrict__ A, const float* __restrict__ B,
               float* __restrict__ F, int* __restrict__ anyflag) {
    const int col_l = threadIdx.x & (CPB - 1);
    const int seg   = threadIdx.x >> 5;          // 0..NSEG-1
    const int cg    = blockIdx.x;                // column group 0..W/CPB-1
    const int m16   = blockIdx.y;                // mask 0..15
    const int col   = cg * CPB + col_l;
    const float* src = (m16 < NIMG) ? (A + (size_t)m16 * H * W)
                                    : (B + (size_t)(m16 - NIMG) * H * W);
    float* f = F + (size_t)m16 * H * W;

    const int row0 = seg * SEG;

    // 1) load 32 rows of this column (independent, coalesced) -> bitmask
    unsigned int m = 0u;
    #pragma unroll
    for (int r = 0; r < SEG; ++r) {
        float px = src[(size_t)(row0 + r) * W + col];
        m |= (px > 0.5f ? 1u : 0u) << r;
    }

    // 2) per-segment summaries (global row index of highest/lowest set bit)
    const int NEG = -(1 << 21);   // sentinel: guarantees distance > 1e6 -> clamps
    const int POS =  (1 << 21);
    __shared__ int s_hi[NSEG][CPB];
    __shared__ int s_lo[NSEG][CPB];
    s_hi[seg][col_l] = m ? (row0 + (31 - __clz((int)m))) : NEG;
    s_lo[seg][col_l] = m ? (row0 + (__ffs((int)m) - 1)) : POS;

    if (__any(m != 0u)) {
        if ((threadIdx.x & 63) == 0) atomicOr(&anyflag[m16], 1);
    }
    __syncthreads();

    // 3) cross-segment carries
    int carry_dn = NEG;
    for (int t = 0; t < seg; ++t) carry_dn = max(carry_dn, s_hi[t][col_l]);
    int carry_up = POS;
    for (int t = seg + 1; t < NSEG; ++t) carry_up = min(carry_up, s_lo[t][col_l]);

    // 4) per-row exact axis-0 distance via bit scans, then clamp+square
    #pragma unroll
    for (int r = 0; r < SEG; ++r) {
        const int ig = row0 + r;
        unsigned int below = m & (0xFFFFFFFFu >> (31 - r));   // bits 0..r
        int pos_dn = below ? (row0 + (31 - __clz((int)below))) : carry_dn;
        unsigned int above = m & (0xFFFFFFFFu << r);          // bits r..31
        int pos_up = above ? (row0 + (__ffs((int)above) - 1)) : carry_up;
        int d = min(ig - pos_dn, pos_up - ig);
        float d1 = fminf((float)d, BIGF);
        f[(size_t)ig * W + col] = d1 * d1;
    }
}

__global__ void k_row_env(const float* __restrict__ A, const float* __restrict__ B,
                          const float* __restrict__ F, float* __restrict__ maxsq) {
    const int row  = blockIdx.x;      // 0..H-1
    const int task = blockIdx.y;      // 0..15
    const int img  = task & 7;
    const int dir  = task >> 3;       // 0: D_b at a-pixels ; 1: D_a at b-pixels
    const int fsel = (dir == 0) ? (NIMG + img) : img;
    const float* frow = F + (size_t)fsel * H * W + (size_t)row * W;
    const float* mrow = ((dir == 0) ? A : B) + (size_t)img * H * W + (size_t)row * W;

    __shared__ float sf[W];
    __shared__ float wmax[8];
    const int j = threadIdx.x;        // 0..W-1, block = 512
    sf[j] = frow[j];
    const bool mk = mrow[j] > 0.5f;
    __syncthreads();

    // exact lower envelope via expanding search with provable cutoff r^2 >= best
    float best = sf[j];
    for (int r = 1; r < W; ++r) {
        float rr = (float)(r * r);
        if (__all(rr >= best)) break;   // wave-uniform exact early exit
        int kl = j - r, kr = j + r;
        if (kl >= 0) best = fminf(best, rr + sf[kl]);
        if (kr < W)  best = fminf(best, rr + sf[kr]);
    }

    float v = mk ? best : 0.0f;
    #pragma unroll
    for (int off = 32; off > 0; off >>= 1)
        v = fmaxf(v, __shfl_down(v, off, 64));
    if ((j & 63) == 0) wmax[j >> 6] = v;
    __syncthreads();
    if (j == 0) {
        float mx = wmax[0];
        #pragma unroll
        for (int w = 1; w < 8; ++w) mx = fmaxf(mx, wmax[w]);
        atomicMax((int*)&maxsq[task], __float_as_int(mx));  // values >= 0
    }
}

__global__ void k_finalize(const float* __restrict__ maxsq, const int* __restrict__ anyflag,
                           float* __restrict__ out) {
    if (threadIdx.x == 0 && blockIdx.x == 0) {
        float s = 0.0f;
        for (int img = 0; img < NIMG; ++img) {
            bool empty = (anyflag[img] == 0) || (anyflag[NIMG + img] == 0);
            float loss;
            if (empty) {
                loss = 1.0f;
            } else {
                float hd = sqrtf(fmaxf(maxsq[img], maxsq[NIMG + img]));
                loss = 1.0f - 1.0f / (1.0f + hd);
            }
            s += loss;
        }
        out[0] = s * (1.0f / (float)NIMG);
    }
}

extern "C" void kernel_launch(void* const* d_in, const int* in_sizes, int n_in,
                              void* d_out, int out_size, void* d_ws, size_t ws_size,
                              hipStream_t stream) {
    const float* A = (const float*)d_in[0];
    const float* B = (const float*)d_in[1];
    float* F       = (float*)d_ws;
    float* maxsq   = F + (size_t)16 * H * W;
    int*   anyflag = (int*)(maxsq + 16);
    float* out     = (float*)d_out;

    hipLaunchKernelGGL(k_init, dim3(1), dim3(32), 0, stream, maxsq, anyflag);
    hipLaunchKernelGGL(k_col_edt, dim3(W / CPB, 16), dim3(CPB * NSEG), 0, stream,
                       A, B, F, anyflag);
    hipLaunchKernelGGL(k_row_env, dim3(H, 16), dim3(W), 0, stream, A, B, F, maxsq);
    hipLaunchKernelGGL(k_finalize, dim3(1), dim3(1), 0, stream, maxsq, anyflag, out);
}